// Round 20
// baseline (443.458 us; speedup 1.0000x reference)
//
#include <hip/hip_runtime.h>
#include <hip/hip_bf16.h>

typedef __attribute__((ext_vector_type(4))) float  f32x4;
typedef __attribute__((ext_vector_type(8))) short  short8;

#define GAS(p) ((const __attribute__((address_space(1))) void*)(p))
#define LAS(p) ((__attribute__((address_space(3))) void*)(p))

__device__ inline short bf16_of(float f) {
    union { float f; unsigned u; } v; v.f = f;
    unsigned r = v.u + 0x7FFFu + ((v.u >> 16) & 1u);   // RNE
    return (short)(r >> 16);
}

#define MFMA __builtin_amdgcn_mfma_f32_16x16x32_bf16

// ============================================================================
// 128x128 BK=64 core (proven): used by proj / pv.
// ============================================================================
__device__ __forceinline__ void stage64(const short* A, long lda,
                                        const short* B, long ldb,
                                        short* As, short* Bs) {
    const int tid = threadIdx.x;
    const int w = tid >> 6, l = tid & 63;
    const int r = l >> 3;
    const int scol = ((l & 7) ^ r) * 8;
#pragma unroll
    for (int q = 0; q < 4; ++q) {
        const int rowb = q * 32 + w * 8;
        __builtin_amdgcn_global_load_lds(GAS(A + (long)(rowb + r) * lda + scol),
                                         LAS(As + rowb * 64), 16, 0, 0);
        __builtin_amdgcn_global_load_lds(GAS(B + (long)(rowb + r) * ldb + scol),
                                         LAS(Bs + rowb * 64), 16, 0, 0);
    }
}

__device__ __forceinline__ void gemm_core64(const short* A, long lda,
                                            const short* B, long ldb, int nk,
                                            short* sA, short* sB,
                                            f32x4 acc[4][4]) {
    const int tid = threadIdx.x;
    const int lane = tid & 63, wid = tid >> 6;
    const int wr = wid >> 1, wc = wid & 1;
    const int fr = lane & 15, fk = lane >> 4;
    const int swz = (fr & 7) << 4;
    const int abase = (wr * 64 + fr) * 128 + fk * 16;
    const int bbase = (wc * 64 + fr) * 128 + fk * 16;

    stage64(A, lda, B, ldb, sA, sB);
    __syncthreads();
    for (int ks = 0; ks < nk; ++ks) {
        const int cur = ks & 1;
        if (ks + 1 < nk)
            stage64(A + (ks + 1) * 64, lda, B + (ks + 1) * 64, ldb,
                    sA + (cur ^ 1) * 8192, sB + (cur ^ 1) * 8192);
        const char* pa = (const char*)(sA + cur * 8192);
        const char* pb = (const char*)(sB + cur * 8192);
        short8 af[2][4], bfr[2][4];
#pragma unroll
        for (int kk = 0; kk < 2; ++kk) {
#pragma unroll
            for (int mi = 0; mi < 4; ++mi)
                af[kk][mi] = *(const short8*)(pa + (((abase + kk * 64) ^ swz) + mi * 2048));
#pragma unroll
            for (int ni = 0; ni < 4; ++ni)
                bfr[kk][ni] = *(const short8*)(pb + (((bbase + kk * 64) ^ swz) + ni * 2048));
        }
#pragma unroll
        for (int kk = 0; kk < 2; ++kk)
#pragma unroll
            for (int mi = 0; mi < 4; ++mi)
#pragma unroll
                for (int ni = 0; ni < 4; ++ni)
                    acc[mi][ni] = MFMA(af[kk][mi], bfr[kk][ni], acc[mi][ni], 0, 0, 0);
        __syncthreads();
    }
}

__device__ __forceinline__ void bounce_store(short* Pb, const short vals[4][4][4],
                                             short* C, long ldc) {
    const int tid = threadIdx.x, lane = tid & 63, wid = tid >> 6;
    const int wr = wid >> 1, wc = wid & 1, fr = lane & 15, fk = lane >> 4;
#pragma unroll
    for (int mi = 0; mi < 4; ++mi)
#pragma unroll
        for (int ni = 0; ni < 4; ++ni)
#pragma unroll
            for (int r = 0; r < 4; ++r) {
                const int row = wr * 64 + mi * 16 + fk * 4 + r;
                const int col = wc * 64 + ni * 16 + fr;
                Pb[row * 128 + (col ^ ((row & 7) << 3))] = vals[mi][ni][r];
            }
    __syncthreads();
#pragma unroll
    for (int i = 0; i < 8; ++i) {
        const int row = i * 16 + (tid >> 4);
        const int ch = tid & 15;
        short8 v = *(const short8*)&Pb[row * 128 + ((ch * 8) ^ ((row & 7) << 3))];
        *(short8*)&C[(long)row * ldc + ch * 8] = v;
    }
}

// ============================================================================
// 256x256 8-phase core (r4/r10 verified): 512 thr / 8 waves (2m x 4n), BK=64,
// counted vmcnt, setprio, swizzled LDS. 128 KB LDS -> 1 block/CU.
// ============================================================================
__device__ __forceinline__ void stage_slab(const short* G, long ld, short* slab) {
    const int w = threadIdx.x >> 6, l = threadIdx.x & 63;
    const int rr = l >> 3, ch = l & 7;
#pragma unroll
    for (int q = 0; q < 4; ++q) {
        const int row = q * 64 + w * 8 + rr;
        __builtin_amdgcn_global_load_lds(GAS(G + (long)row * ld + ((ch ^ (row & 7)) * 8)),
                                         LAS(slab + (q * 64 + w * 8) * 64), 16, 0, 0);
    }
}

__device__ __forceinline__ short8 lds_frag(const short* slab, int row, int c) {
    return *(const short8*)((const char*)slab + row * 128 + ((c ^ (row & 7)) * 16));
}

#define PH_FENCE asm volatile("" ::: "memory")

template<int KK, int MH, bool RB>
__device__ __forceinline__ void phase_block(const short* a, const short* b,
                                            int wm, int wn, int fr, int fk,
                                            short8 (&bf)[4], f32x4 (&acc)[8][4]) {
    short8 af[4];
#pragma unroll
    for (int m = 0; m < 4; ++m)
        af[m] = lds_frag(a, wm * 128 + MH * 64 + m * 16 + fr, KK * 4 + fk);
    if (RB) {
#pragma unroll
        for (int n = 0; n < 4; ++n)
            bf[n] = lds_frag(b, wn * 64 + n * 16 + fr, KK * 4 + fk);
    }
    PH_FENCE; __builtin_amdgcn_s_barrier();
    asm volatile("s_waitcnt lgkmcnt(0)" ::: "memory");
    __builtin_amdgcn_sched_barrier(0);
    __builtin_amdgcn_s_setprio(1);
#pragma unroll
    for (int m = 0; m < 4; ++m)
#pragma unroll
        for (int n = 0; n < 4; ++n)
            acc[MH * 4 + m][n] = MFMA(af[m], bf[n], acc[MH * 4 + m][n], 0, 0, 0);
    __builtin_amdgcn_s_setprio(0);
    PH_FENCE; __builtin_amdgcn_s_barrier(); PH_FENCE;
}

template<int KK, int MH>
__device__ __forceinline__ void phase3_block(const short* a, const short* Bg, long ldb,
                                             short* stage_dst, bool do_stage,
                                             int wm, int wn, int fr, int fk,
                                             short8 (&bf)[4], f32x4 (&acc)[8][4]) {
    short8 af[4];
#pragma unroll
    for (int m = 0; m < 4; ++m)
        af[m] = lds_frag(a, wm * 128 + MH * 64 + m * 16 + fr, KK * 4 + fk);
    if (do_stage) {
        stage_slab(Bg, ldb, stage_dst);
        asm volatile("s_waitcnt vmcnt(4)" ::: "memory");
    } else {
        asm volatile("s_waitcnt vmcnt(0)" ::: "memory");
    }
    __builtin_amdgcn_sched_barrier(0);
    PH_FENCE; __builtin_amdgcn_s_barrier();
    asm volatile("s_waitcnt lgkmcnt(0)" ::: "memory");
    __builtin_amdgcn_sched_barrier(0);
    __builtin_amdgcn_s_setprio(1);
#pragma unroll
    for (int m = 0; m < 4; ++m)
#pragma unroll
        for (int n = 0; n < 4; ++n)
            acc[MH * 4 + m][n] = MFMA(af[m], bf[n], acc[MH * 4 + m][n], 0, 0, 0);
    __builtin_amdgcn_s_setprio(0);
    PH_FENCE; __builtin_amdgcn_s_barrier(); PH_FENCE;
}

__device__ __forceinline__ void gemm256_core(const short* Ag, long lda,
                                             const short* Bg, long ldb, int nk,
                                             short* lds, f32x4 (&acc)[8][4]) {
    short* sA = lds;            // 2 x 16384 elems
    short* sB = lds + 32768;    // 2 x 16384 elems
    const int tid = threadIdx.x, lane = tid & 63, w = tid >> 6;
    const int wm = w >> 2, wn = w & 3, fr = lane & 15, fk = lane >> 4;

    stage_slab(Bg, ldb, sB);
    stage_slab(Ag, lda, sA);
    stage_slab(Bg + 64, ldb, sB + 16384);
    asm volatile("s_waitcnt vmcnt(4)" ::: "memory");
    __builtin_amdgcn_sched_barrier(0);
    PH_FENCE; __builtin_amdgcn_s_barrier(); PH_FENCE;

    short8 bf[4];
    for (int t = 0; t < nk; ++t) {
        const short* a = sA + (t & 1) * 16384;
        const short* b = sB + (t & 1) * 16384;
        if (t + 1 < nk)
            stage_slab(Ag + (long)(t + 1) * 64, lda, sA + ((t + 1) & 1) * 16384);
        phase_block<0, 0, true >(a, b, wm, wn, fr, fk, bf, acc);
        phase_block<0, 1, false>(a, b, wm, wn, fr, fk, bf, acc);
        phase_block<1, 0, true >(a, b, wm, wn, fr, fk, bf, acc);
        phase3_block<1, 1>(a, Bg + (long)(t + 2) * 64, ldb, sB + (t & 1) * 16384,
                           t + 2 < nk, wm, wn, fr, fk, bf, acc);
    }
}

__device__ __forceinline__ void wave_tile_store(const short* wbuf, short* Cw, long ldc) {
    const int l = threadIdx.x & 63, rr = l >> 3, ch = l & 7;
#pragma unroll
    for (int p = 0; p < 16; ++p) {
        const int row = p * 8 + rr;
        short8 v = *(const short8*)((const char*)wbuf + row * 128 + ((ch ^ (row & 7)) * 16));
        *(short8*)&Cw[(long)row * ldc + ch * 8] = v;
    }
}

// ---------- merged Q|K projection ----------
__global__ __launch_bounds__(256, 2)
void proj_qk_k(const short* __restrict__ xb, const short* __restrict__ WqkT,
               short* __restrict__ Qb, short* __restrict__ Kb,
               const float* __restrict__ bq, const float* __restrict__ bk) {
    __shared__ short sA[2 * 8192], sB[2 * 8192];
    const short* Ab = xb + (long)blockIdx.x * 128 * 512;
    const short* Bb = WqkT + (long)blockIdx.y * 128 * 512;
    f32x4 acc[4][4] = {};
    gemm_core64(Ab, 512, Bb, 512, 8, sA, sB, acc);

    const int lane = threadIdx.x & 63, wid = threadIdx.x >> 6;
    const int wc = wid & 1, fr = lane & 15;
    const int qc0 = blockIdx.y * 128;
    const float* bias = qc0 < 512 ? bq + qc0 : bk + (qc0 - 512);
    short vals[4][4][4];
#pragma unroll
    for (int mi = 0; mi < 4; ++mi)
#pragma unroll
        for (int ni = 0; ni < 4; ++ni) {
            const float bv_ = bias[wc * 64 + ni * 16 + fr];
#pragma unroll
            for (int r = 0; r < 4; ++r)
                vals[mi][ni][r] = bf16_of(acc[mi][ni][r] + bv_);
        }
    short* dst = (qc0 < 512 ? Qb + qc0 : Kb + (qc0 - 512)) + (long)blockIdx.x * 128 * 512;
    bounce_store(sA, vals, dst, 512);
}

// ---------- V^T projection ----------
__global__ __launch_bounds__(256, 2)
void proj_vt_k(const short* __restrict__ WvT, const short* __restrict__ xb,
               short* __restrict__ VT, const float* __restrict__ bv) {
    __shared__ short sA[2 * 8192], sB[2 * 8192];
    const short* Ab = WvT + (long)blockIdx.x * 128 * 512;
    const short* Bb = xb + (long)blockIdx.y * 128 * 512;
    f32x4 acc[4][4] = {};
    gemm_core64(Ab, 512, Bb, 512, 8, sA, sB, acc);

    const int lane = threadIdx.x & 63, wid = threadIdx.x >> 6;
    const int wr = wid >> 1, fk = lane >> 4;
    short vals[4][4][4];
#pragma unroll
    for (int mi = 0; mi < 4; ++mi)
#pragma unroll
        for (int ni = 0; ni < 4; ++ni)
#pragma unroll
            for (int r = 0; r < 4; ++r) {
                const int rowg = blockIdx.x * 128 + wr * 64 + mi * 16 + fk * 4 + r;
                vals[mi][ni][r] = bf16_of(acc[mi][ni][r] + bv[rowg]);
            }
    bounce_store(sA, vals, VT + (long)blockIdx.x * 128 * 24576 + blockIdx.y * 128, 24576);
}

struct Off6 { long a[6], b[6]; };
struct POff { long v[6], c[6]; };

// ---------- QK^T (256² 8-phase) big-dispatch: grid (8,8,nsl) ----------
__global__ __launch_bounds__(512, 2)
void qk256(const short* __restrict__ Qb, const short* __restrict__ Kb,
           short* __restrict__ Sc, float* __restrict__ lpart,
           Off6 o, int z0, float kscale) {
    __shared__ short lds[65536];
    const int bx = blockIdx.x, by = blockIdx.y, z = blockIdx.z;
    const int slice = z0 + z;
    const int gp = slice >> 2, b = slice & 3;
    const short* Ag = Qb + o.a[gp] + ((long)b * 2048 + (long)bx * 256) * 512;
    const short* Bg = Kb + o.b[gp] + ((long)b * 2048 + (long)by * 256) * 512;
    f32x4 acc[8][4] = {};
    gemm256_core(Ag, 512, Bg, 512, 8, lds, acc);

    const int tid = threadIdx.x, lane = tid & 63, w = tid >> 6;
    const int wm = w >> 2, wn = w & 3, fr = lane & 15, fk = lane >> 4;

#pragma unroll
    for (int m = 0; m < 8; ++m)
#pragma unroll
        for (int n = 0; n < 4; ++n)
#pragma unroll
            for (int r = 0; r < 4; ++r)
                acc[m][n][r] = exp2f(acc[m][n][r] * kscale);

    float* lp = lpart + ((long)z * 32 + by * 4 + wn) * 2048 + (long)bx * 256 + wm * 128;
#pragma unroll
    for (int m = 0; m < 8; ++m)
#pragma unroll
        for (int r = 0; r < 4; ++r) {
            float s = acc[m][0][r] + acc[m][1][r] + acc[m][2][r] + acc[m][3][r];
            s += __shfl_xor(s, 1); s += __shfl_xor(s, 2);
            s += __shfl_xor(s, 4); s += __shfl_xor(s, 8);
            if (fr == 0) lp[m * 16 + fk * 4 + r] = s;
        }

    short* wbuf = lds + w * 8192;
#pragma unroll
    for (int m = 0; m < 8; ++m)
#pragma unroll
        for (int n = 0; n < 4; ++n)
#pragma unroll
            for (int r = 0; r < 4; ++r) {
                const int row = m * 16 + fk * 4 + r, col = n * 16 + fr;
                *(short*)((char*)wbuf + ((row * 128 + col * 2) ^ ((row & 7) << 4))) = bf16_of(acc[m][n][r]);
            }
    short* Cw = Sc + (long)z * 2048 * 2048 + ((long)bx * 256 + wm * 128) * 2048
                + by * 256 + wn * 64;
    wave_tile_store(wbuf, Cw, 2048);
}

// ---------- QK^T fallback (128², BK=32, zero-conflict swizzle, pow2 nsl) ----------
__global__ __launch_bounds__(256, 4)
void qk_exp(const short* __restrict__ Qb, const short* __restrict__ Kb,
            short* __restrict__ Sc, float* __restrict__ lpart,
            Off6 o, int z0, int zmask, int zshift, float kscale) {
    __shared__ short lds[16384];
    short* As = lds;
    short* Bs = lds + 8192;
    const int bid = blockIdx.x;
    const int z = bid & zmask;
    const int t = bid >> zshift;
    const int bx = t & 15, by = t >> 4;
    const int slice = z0 + z;
    const int gp = slice >> 2, b = slice & 3;
    const short* A = Qb + o.a[gp] + ((long)b * 2048 + (long)bx * 128) * 512;
    const short* B = Kb + o.b[gp] + ((long)b * 2048 + (long)by * 128) * 512;

    const int tid = threadIdx.x, lane = tid & 63, wid = tid >> 6;
    const int wr = wid >> 1, wc = wid & 1, fr = lane & 15, fk = lane >> 4;
    const int sr = tid >> 2;
    const int scc = (((tid & 3) ^ ((sr >> 1) & 3)) * 8);
    const int arow = wr * 64 + fr, brow = wc * 64 + fr;

    auto stage = [&](const short* Ap, const short* Bp, int cur) {
        short* ad = As + cur * 4096;
        short* bd = Bs + cur * 4096;
        __builtin_amdgcn_global_load_lds(GAS(Ap + (long)sr * 512 + scc),
                                         LAS(ad + sr * 32 + (tid & 3) * 8), 16, 0, 0);
        __builtin_amdgcn_global_load_lds(GAS(Ap + (long)(sr + 64) * 512 + scc),
                                         LAS(ad + (sr + 64) * 32 + (tid & 3) * 8), 16, 0, 0);
        __builtin_amdgcn_global_load_lds(GAS(Bp + (long)sr * 512 + scc),
                                         LAS(bd + sr * 32 + (tid & 3) * 8), 16, 0, 0);
        __builtin_amdgcn_global_load_lds(GAS(Bp + (long)(sr + 64) * 512 + scc),
                                         LAS(bd + (sr + 64) * 32 + (tid & 3) * 8), 16, 0, 0);
    };

    f32x4 acc[4][4] = {};
    stage(A, B, 0);
    __syncthreads();
    for (int ks = 0; ks < 16; ++ks) {
        const int cur = ks & 1;
        if (ks + 1 < 16) stage(A + (ks + 1) * 32, B + (ks + 1) * 32, cur ^ 1);
        const short* pa = As + cur * 4096;
        const short* pb = Bs + cur * 4096;
        short8 af[4], bf[4];
#pragma unroll
        for (int mi = 0; mi < 4; ++mi) {
            const int row = arow + mi * 16;
            af[mi] = *(const short8*)&pa[row * 32 + ((fk ^ ((row >> 1) & 3)) * 8)];
        }
#pragma unroll
        for (int ni = 0; ni < 4; ++ni) {
            const int row = brow + ni * 16;
            bf[ni] = *(const short8*)&pb[row * 32 + ((fk ^ ((row >> 1) & 3)) * 8)];
        }
#pragma unroll
        for (int mi = 0; mi < 4; ++mi)
#pragma unroll
            for (int ni = 0; ni < 4; ++ni)
                acc[mi][ni] = MFMA(af[mi], bf[ni], acc[mi][ni], 0, 0, 0);
        __syncthreads();
    }

#pragma unroll
    for (int mi = 0; mi < 4; ++mi)
#pragma unroll
        for (int ni = 0; ni < 4; ++ni)
#pragma unroll
            for (int r = 0; r < 4; ++r)
                acc[mi][ni][r] = exp2f(acc[mi][ni][r] * kscale);

#pragma unroll
    for (int mi = 0; mi < 4; ++mi)
#pragma unroll
        for (int r = 0; r < 4; ++r) {
            float s = acc[mi][0][r] + acc[mi][1][r] + acc[mi][2][r] + acc[mi][3][r];
            s += __shfl_xor(s, 1); s += __shfl_xor(s, 2);
            s += __shfl_xor(s, 4); s += __shfl_xor(s, 8);
            if (fr == 0)
                lpart[((long)z * 32 + by * 2 + wc) * 2048 +
                      (long)bx * 128 + wr * 64 + mi * 16 + fk * 4 + r] = s;
        }

    short vals[4][4][4];
#pragma unroll
    for (int mi = 0; mi < 4; ++mi)
#pragma unroll
        for (int ni = 0; ni < 4; ++ni)
#pragma unroll
            for (int r = 0; r < 4; ++r)
                vals[mi][ni][r] = bf16_of(acc[mi][ni][r]);

    short* Cb = Sc + (long)z * 2048 * 2048 +
                (long)bx * 128 * 2048 + (long)by * 128;
    bounce_store(lds, vals, Cb, 2048);
}

// ---------- P @ V, in-kernel l reduction; z = bid % nsl (any nsl) ----------
__global__ __launch_bounds__(256, 2)
void pv_div(const short* __restrict__ Sc, const short* __restrict__ VT,
            const float* __restrict__ lpart, short* __restrict__ F,
            POff o, int z0, int nsl) {
    __shared__ short sA[2 * 8192], sB[2 * 8192];
    const unsigned bid = blockIdx.x, nslu = (unsigned)nsl;
    const int z = bid % nslu;
    const int t = bid / nslu;
    const int bx = t & 15, by = t >> 4;
    const int slice = z0 + z;
    const int gp = slice >> 2, b = slice & 3;
    const short* Ab = Sc + (long)z * 2048 * 2048 + (long)bx * 128 * 2048;
    const short* Bb = VT + o.v[gp] + (long)b * 2048 + (long)by * 128 * 24576;
    f32x4 acc[4][4] = {};
    gemm_core64(Ab, 2048, Bb, 24576, 32, sA, sB, acc);

    const int tid = threadIdx.x, lane = tid & 63, wid = tid >> 6;
    const int wr = wid >> 1, wc = wid & 1, fr = lane & 15, fk = lane >> 4;

    float* linv_s = (float*)sB;
    if (tid < 128) {
        const float* lp = lpart + ((long)z * 32) * 2048 + (long)bx * 128 + tid;
        float s = 0.f;
#pragma unroll
        for (int j = 0; j < 32; ++j) s += lp[(long)j * 2048];
        linv_s[tid] = 1.0f / s;
    }
    __syncthreads();

    short vals[4][4][4];
#pragma unroll
    for (int mi = 0; mi < 4; ++mi) {
        float linv[4];
#pragma unroll
        for (int r = 0; r < 4; ++r) linv[r] = linv_s[wr * 64 + mi * 16 + fk * 4 + r];
#pragma unroll
        for (int ni = 0; ni < 4; ++ni)
#pragma unroll
            for (int r = 0; r < 4; ++r)
                vals[mi][ni][r] = bf16_of(acc[mi][ni][r] * linv[r]);
    }
    __syncthreads();

    short* Cb = F + ((long)b * 2048 + (long)bx * 128) * 3072 +
                o.c[gp] + (long)by * 128;
    bounce_store(sA, vals, Cb, 3072);
}

// ============================================================================
// final: d_out[8192][512] = fused[8192][3072] @ WoT2^T + bo (f32).
// ============================================================================
__device__ __forceinline__ void stage_f(const short* A, const short* B,
                                        short* As, short* Bs) {
    const int tid = threadIdx.x, w = tid >> 6, l = tid & 63;
    const int r = l >> 3, scol = ((l & 7) ^ r) * 8;
#pragma unroll
    for (int q = 0; q < 4; ++q) {
        const int rowb = q * 32 + w * 8;
        __builtin_amdgcn_global_load_lds(GAS(A + (long)(rowb + r) * 3072 + scol),
                                         LAS(As + rowb * 64), 16, 0, 0);
    }
#pragma unroll
    for (int q = 0; q < 2; ++q) {
        const int rowb = q * 32 + w * 8;
        __builtin_amdgcn_global_load_lds(GAS(B + (long)(rowb + r) * 3072 + scol),
                                         LAS(Bs + rowb * 64), 16, 0, 0);
    }
}

__global__ __launch_bounds__(256, 3)
void final64(const short* __restrict__ A, const short* __restrict__ B,
             float* __restrict__ C, const float* __restrict__ bias) {
    __shared__ short sA[2 * 8192], sB[2 * 4096];
    const short* Ab = A + (long)blockIdx.x * 128 * 3072;
    const short* Bb = B + (long)blockIdx.y * 64 * 3072;
    const int tid = threadIdx.x, lane = tid & 63, w = tid >> 6;
    const int fr = lane & 15, fk = lane >> 4;
    const int swz = (fr & 7) << 4;
    const int abase = (w * 32 + fr) * 128 + fk * 16;
    const int bbase = fr * 128 + fk * 16;

    f32x4 acc[2][4] = {};
    stage_f(Ab, Bb, sA, sB);
    __syncthreads();
    for (int ks = 0; ks < 48; ++ks) {
        const int cur = ks & 1;
        if (ks + 1 < 48)
            stage_f(Ab + (ks + 1) * 64, Bb + (ks + 1) * 64,
                    sA + (cur ^ 1) * 8192, sB + (cur ^ 1) * 4096);
        const char* pa = (const char*)(sA + cur * 8192);
        const char* pb = (const char*)(sB + cur * 4096);
        short8 af[2][2], bf[2][4];
#pragma unroll
        for (int kk = 0; kk < 2; ++kk) {
#pragma unroll
            for (int mi = 0; mi < 2; ++mi)
                af[kk][mi] = *(const short8*)(pa + (((abase + kk * 64) ^ swz) + mi * 2048));
#pragma unroll
            for (int ni = 0; ni < 4; ++ni)
                bf[kk][ni] = *(const short8*)(pb + (((bbase + kk * 64) ^ swz) + ni * 2048));
        }
#pragma unroll
        for (int kk = 0; kk < 2; ++kk)
#pragma unroll
            for (int mi = 0; mi < 2; ++mi)
#pragma unroll
                for (int ni = 0; ni < 4; ++ni)
                    acc[mi][ni] = MFMA(af[kk][mi], bf[kk][ni], acc[mi][ni], 0, 0, 0);
        __syncthreads();
    }
    const long r0 = (long)blockIdx.x * 128 + w * 32 + fk * 4;
    const long c0 = (long)blockIdx.y * 64 + fr;
#pragma unroll
    for (int mi = 0; mi < 2; ++mi)
#pragma unroll
        for (int ni = 0; ni < 4; ++ni) {
            const long rr = r0 + mi * 16, cc = c0 + ni * 16;
#pragma unroll
            for (int r = 0; r < 4; ++r)
                C[(rr + r) * 512 + cc] = acc[mi][ni][r] + bias[cc];
        }
}

// ---------- f32 -> bf16 convert of x1,x2,x3 ----------
__global__ __launch_bounds__(256)
void xconv(const float* __restrict__ x0, const float* __restrict__ x1,
           const float* __restrict__ x2, short* __restrict__ xb) {
    const float* s = blockIdx.z == 0 ? x0 : (blockIdx.z == 1 ? x1 : x2);
    const long i = ((long)blockIdx.x * 256 + threadIdx.x) * 8;
    f32x4 a = *(const f32x4*)(s + i), c = *(const f32x4*)(s + i + 4);
    short8 v;
    v[0] = bf16_of(a.x); v[1] = bf16_of(a.y); v[2] = bf16_of(a.z); v[3] = bf16_of(a.w);
    v[4] = bf16_of(c.x); v[5] = bf16_of(c.y); v[6] = bf16_of(c.z); v[7] = bf16_of(c.w);
    *(short8*)(xb + (long)blockIdx.z * 8192 * 512 + i) = v;
}

// ---------- all weight transposes in one launch ----------
__global__ __launch_bounds__(256)
void wprep(const float* __restrict__ Wq, const float* __restrict__ Wk,
           const float* __restrict__ Wv, const float* __restrict__ Wo,
           short* __restrict__ WqkT, short* __restrict__ WvT,
           short* __restrict__ WoT2) {
    __shared__ float t[32][33];
    const int z = blockIdx.z;
    const float* src; short* dst; int rows; long ldd; bool dup = false;
    if (z == 0)      { src = Wq; dst = WqkT;              rows = 512;  ldd = 512; }
    else if (z == 1) { src = Wk; dst = WqkT + 512L * 512; rows = 512;  ldd = 512; }
    else if (z == 2) { src = Wv; dst = WvT;               rows = 512;  ldd = 512; }
    else             { src = Wo; dst = WoT2;              rows = 1536; ldd = 3072; dup = true; }
    const int r0 = blockIdx.x * 32, c0 = blockIdx.y * 32;
    if (r0 >= rows) return;
    const int lx = threadIdx.x & 31, ly = threadIdx.x >> 5;
#pragma unroll
    for (int p = 0; p < 4; ++p)
        t[ly + 8 * p][lx] = src[(long)(r0 + ly + 8 * p) * 512 + (c0 + lx)];
    __syncthreads();
#pragma unroll
    for (int p = 0; p < 4; ++p) {
        const short v = bf16_of(t[lx][ly + 8 * p]);
        const long base = (long)(c0 + ly + 8 * p) * ldd + (r0 + lx);
        dst[base] = v;
        if (dup) dst[base + 1536] = v;
    }
}

// ============================================================================
extern "C" void kernel_launch(void* const* d_in, const int* in_sizes, int n_in,
                              void* d_out, int out_size, void* d_ws, size_t ws_size,
                              hipStream_t stream) {
    const float* x[3] = { (const float*)d_in[0], (const float*)d_in[1], (const float*)d_in[2] };
    const float* Wq = (const float*)d_in[3]; const float* bq = (const float*)d_in[4];
    const float* Wk = (const float*)d_in[5]; const float* bk = (const float*)d_in[6];
    const float* Wv = (const float*)d_in[7]; const float* bv = (const float*)d_in[8];
    const float* Wo = (const float*)d_in[9]; const float* bo = (const float*)d_in[10];

    const long TOK = 8192, T3 = 3 * TOK;

    char* ws = (char*)d_ws;
    size_t off = 0;
    auto alloc = [&](size_t bytes) -> void* {
        void* pp = ws + off;
        off += (bytes + 255) & ~(size_t)255;
        return pp;
    };

    short* WqkT  = (short*)alloc(1024L * 512 * 2);        // [1024][512] = [WqT; WkT]
    short* WvT   = (short*)alloc(512L * 512 * 2);
    short* WoT2  = (short*)alloc(512L * 3072 * 2);        // [512][3072] = [WoT | WoT]
    short* Qb    = (short*)alloc(T3 * 512 * 2);           // [24576][512]
    short* Kb    = (short*)alloc(T3 * 512 * 2);           // [24576][512]
    short* VT    = (short*)alloc(512L * T3 * 2);          // [512][24576]
    short* fused = (short*)alloc(TOK * 3072 * 2);         // [8192][3072]
    float* lpart = (float*)alloc(12L * 32 * 2048 * 4);    // up to 12 slices
    short* xb    = (short*)alloc(T3 * 512 * 2);

    const size_t SLICE = 2048L * 2048 * 2;                // 8.39 MB
    const size_t rem = ws_size > off ? ws_size - off : 0;
    int nsl;
    if      (rem >= 12 * SLICE) nsl = 12;                 // qk256 big-dispatch tier
    else if (rem >=  8 * SLICE) nsl = 8;                  // 128² chunked fallback
    else                        nsl = 4;
    short* scores = (short*)alloc((size_t)nsl * SLICE);

    const dim3 tb(256);
    wprep<<<dim3(48, 16, 4), tb, 0, stream>>>(Wq, Wk, Wv, Wo, WqkT, WvT, WoT2);
    xconv<<<dim3(2048, 1, 3), tb, 0, stream>>>(x[0], x[1], x[2], xb);

    proj_qk_k<<<dim3(192, 8), tb, 0, stream>>>(xb, WqkT, Qb, Kb, bq, bk);
    proj_vt_k<<<dim3(4, 192), tb, 0, stream>>>(WvT, xb, VT, bv);

    // pairs: i attends to j. gp 0..2 -> fused cols [im*512); gp 3..5 -> +1536.
    const int imap[6] = {0, 1, 2, 0, 1, 2};
    const int jmap[6] = {1, 0, 0, 2, 2, 1};
    Off6 qo{}; POff po{};
    for (int gp = 0; gp < 6; ++gp) {
        qo.a[gp] = (long)imap[gp] * TOK * 512;
        qo.b[gp] = (long)jmap[gp] * TOK * 512;
        po.v[gp] = (long)jmap[gp] * TOK;
        po.c[gp] = (long)imap[gp] * 512 + (gp >= 3 ? 1536 : 0);
    }
    const float kscale = 0.04419417382415922f * 1.4426950408889634f; // 1/sqrt(512)*log2e

    if (nsl == 12) {
        for (int c = 0; c < 24; c += 12) {
            qk256<<<dim3(8, 8, 12), dim3(512), 0, stream>>>(Qb, Kb, scores, lpart,
                                                            qo, c, kscale);
            pv_div<<<dim3(64 * 12), tb, 0, stream>>>(scores, VT, lpart, fused,
                                                     po, c, 12);
        }
    } else {
        const int zshift = (nsl == 8) ? 3 : 2;
        for (int z0 = 0; z0 < 24; z0 += nsl) {
            qk_exp<<<dim3(256 * nsl), tb, 0, stream>>>(Qb, Kb, scores, lpart, qo,
                                                       z0, nsl - 1, zshift, kscale);
            pv_div<<<dim3(64 * nsl), tb, 0, stream>>>(scores, VT, lpart, fused,
                                                      po, z0, nsl);
        }
    }

    final64<<<dim3(64, 8), tb, 0, stream>>>(fused, WoT2, (float*)d_out, bo);
}

// Round 21
// 399.158 us; speedup vs baseline: 1.1110x; 1.1110x over previous
//
#include <hip/hip_runtime.h>
#include <hip/hip_bf16.h>

typedef __attribute__((ext_vector_type(4))) float  f32x4;
typedef __attribute__((ext_vector_type(8))) short  short8;

#define GAS(p) ((const __attribute__((address_space(1))) void*)(p))
#define LAS(p) ((__attribute__((address_space(3))) void*)(p))

__device__ inline short bf16_of(float f) {
    union { float f; unsigned u; } v; v.f = f;
    unsigned r = v.u + 0x7FFFu + ((v.u >> 16) & 1u);   // RNE
    return (short)(r >> 16);
}

#define MFMA __builtin_amdgcn_mfma_f32_16x16x32_bf16

// ============================================================================
// 128x128 BK=64 core (proven): global_load_lds staging, pre-swizzled source,
// swizzled ds_read_b128 -> conflict-free. Used by proj / pv.
// ============================================================================
__device__ __forceinline__ void stage64(const short* A, long lda,
                                        const short* B, long ldb,
                                        short* As, short* Bs) {
    const int tid = threadIdx.x;
    const int w = tid >> 6, l = tid & 63;
    const int r = l >> 3;
    const int scol = ((l & 7) ^ r) * 8;
#pragma unroll
    for (int q = 0; q < 4; ++q) {
        const int rowb = q * 32 + w * 8;
        __builtin_amdgcn_global_load_lds(GAS(A + (long)(rowb + r) * lda + scol),
                                         LAS(As + rowb * 64), 16, 0, 0);
        __builtin_amdgcn_global_load_lds(GAS(B + (long)(rowb + r) * ldb + scol),
                                         LAS(Bs + rowb * 64), 16, 0, 0);
    }
}

__device__ __forceinline__ void gemm_core64(const short* A, long lda,
                                            const short* B, long ldb, int nk,
                                            short* sA, short* sB,
                                            f32x4 acc[4][4]) {
    const int tid = threadIdx.x;
    const int lane = tid & 63, wid = tid >> 6;
    const int wr = wid >> 1, wc = wid & 1;
    const int fr = lane & 15, fk = lane >> 4;
    const int swz = (fr & 7) << 4;
    const int abase = (wr * 64 + fr) * 128 + fk * 16;
    const int bbase = (wc * 64 + fr) * 128 + fk * 16;

    stage64(A, lda, B, ldb, sA, sB);
    __syncthreads();
    for (int ks = 0; ks < nk; ++ks) {
        const int cur = ks & 1;
        if (ks + 1 < nk)
            stage64(A + (ks + 1) * 64, lda, B + (ks + 1) * 64, ldb,
                    sA + (cur ^ 1) * 8192, sB + (cur ^ 1) * 8192);
        const char* pa = (const char*)(sA + cur * 8192);
        const char* pb = (const char*)(sB + cur * 8192);
        short8 af[2][4], bfr[2][4];
#pragma unroll
        for (int kk = 0; kk < 2; ++kk) {
#pragma unroll
            for (int mi = 0; mi < 4; ++mi)
                af[kk][mi] = *(const short8*)(pa + (((abase + kk * 64) ^ swz) + mi * 2048));
#pragma unroll
            for (int ni = 0; ni < 4; ++ni)
                bfr[kk][ni] = *(const short8*)(pb + (((bbase + kk * 64) ^ swz) + ni * 2048));
        }
#pragma unroll
        for (int kk = 0; kk < 2; ++kk)
#pragma unroll
            for (int mi = 0; mi < 4; ++mi)
#pragma unroll
                for (int ni = 0; ni < 4; ++ni)
                    acc[mi][ni] = MFMA(af[kk][mi], bfr[kk][ni], acc[mi][ni], 0, 0, 0);
        __syncthreads();
    }
}

__device__ __forceinline__ void bounce_store(short* Pb, const short vals[4][4][4],
                                             short* C, long ldc) {
    const int tid = threadIdx.x, lane = tid & 63, wid = tid >> 6;
    const int wr = wid >> 1, wc = wid & 1, fr = lane & 15, fk = lane >> 4;
#pragma unroll
    for (int mi = 0; mi < 4; ++mi)
#pragma unroll
        for (int ni = 0; ni < 4; ++ni)
#pragma unroll
            for (int r = 0; r < 4; ++r) {
                const int row = wr * 64 + mi * 16 + fk * 4 + r;
                const int col = wc * 64 + ni * 16 + fr;
                Pb[row * 128 + (col ^ ((row & 7) << 3))] = vals[mi][ni][r];
            }
    __syncthreads();
#pragma unroll
    for (int i = 0; i < 8; ++i) {
        const int row = i * 16 + (tid >> 4);
        const int ch = tid & 15;
        short8 v = *(const short8*)&Pb[row * 128 + ((ch * 8) ^ ((row & 7) << 3))];
        *(short8*)&C[(long)row * ldc + ch * 8] = v;
    }
}

// ---------- merged Q|K projection ----------
__global__ __launch_bounds__(256, 2)
void proj_qk_k(const short* __restrict__ xb, const short* __restrict__ WqkT,
               short* __restrict__ Qb, short* __restrict__ Kb,
               const float* __restrict__ bq, const float* __restrict__ bk) {
    __shared__ short sA[2 * 8192], sB[2 * 8192];
    const short* Ab = xb + (long)blockIdx.x * 128 * 512;
    const short* Bb = WqkT + (long)blockIdx.y * 128 * 512;
    f32x4 acc[4][4] = {};
    gemm_core64(Ab, 512, Bb, 512, 8, sA, sB, acc);

    const int lane = threadIdx.x & 63, wid = threadIdx.x >> 6;
    const int wc = wid & 1, fr = lane & 15;
    const int qc0 = blockIdx.y * 128;
    const float* bias = qc0 < 512 ? bq + qc0 : bk + (qc0 - 512);
    short vals[4][4][4];
#pragma unroll
    for (int mi = 0; mi < 4; ++mi)
#pragma unroll
        for (int ni = 0; ni < 4; ++ni) {
            const float bv_ = bias[wc * 64 + ni * 16 + fr];
#pragma unroll
            for (int r = 0; r < 4; ++r)
                vals[mi][ni][r] = bf16_of(acc[mi][ni][r] + bv_);
        }
    short* dst = (qc0 < 512 ? Qb + qc0 : Kb + (qc0 - 512)) + (long)blockIdx.x * 128 * 512;
    bounce_store(sA, vals, dst, 512);
}

// ---------- V^T projection ----------
__global__ __launch_bounds__(256, 2)
void proj_vt_k(const short* __restrict__ WvT, const short* __restrict__ xb,
               short* __restrict__ VT, const float* __restrict__ bv) {
    __shared__ short sA[2 * 8192], sB[2 * 8192];
    const short* Ab = WvT + (long)blockIdx.x * 128 * 512;
    const short* Bb = xb + (long)blockIdx.y * 128 * 512;
    f32x4 acc[4][4] = {};
    gemm_core64(Ab, 512, Bb, 512, 8, sA, sB, acc);

    const int lane = threadIdx.x & 63, wid = threadIdx.x >> 6;
    const int wr = wid >> 1, fk = lane >> 4;
    short vals[4][4][4];
#pragma unroll
    for (int mi = 0; mi < 4; ++mi)
#pragma unroll
        for (int ni = 0; ni < 4; ++ni)
#pragma unroll
            for (int r = 0; r < 4; ++r) {
                const int rowg = blockIdx.x * 128 + wr * 64 + mi * 16 + fk * 4 + r;
                vals[mi][ni][r] = bf16_of(acc[mi][ni][r] + bv[rowg]);
            }
    bounce_store(sA, vals, VT + (long)blockIdx.x * 128 * 24576 + blockIdx.y * 128, 24576);
}

// ============================================================================
// qk_exp (m97-class BK=32): LDS = A[2][128][32] + B[2][128][32] = 32 KB total
// -> 4 blocks/CU (the measured optimum). Chunk-swizzled staging (row&3
// involution, both sides); bounce reuses the full 32KB after the K-loop.
// Flat grid + XCD pinning.
// ============================================================================
struct Off6 { long a[6], b[6]; };

__global__ __launch_bounds__(256, 4)
void qk_exp(const short* __restrict__ Qb, const short* __restrict__ Kb,
            short* __restrict__ Sc, float* __restrict__ lpart,
            Off6 o, int z0, int zmask, int zshift, float kscale) {
    __shared__ short lds[16384];           // 32 KB
    short* As = lds;                        // [2][4096]
    short* Bs = lds + 8192;                 // [2][4096]
    const int bid = blockIdx.x;
    const int z = bid & zmask;
    const int t = bid >> zshift;
    const int bx = t & 15, by = t >> 4;
    const int slice = z0 + z;
    const int gp = slice >> 2, b = slice & 3;
    const short* A = Qb + o.a[gp] + ((long)b * 2048 + (long)bx * 128) * 512;
    const short* B = Kb + o.b[gp] + ((long)b * 2048 + (long)by * 128) * 512;

    const int tid = threadIdx.x, lane = tid & 63, wid = tid >> 6;
    const int wr = wid >> 1, wc = wid & 1, fr = lane & 15, fk = lane >> 4;
    const int sr = tid >> 2;                       // staging row 0..63
    const int scc = (((tid & 3) ^ (sr & 3)) * 8);  // pre-swizzled source chunk
    const int arow = wr * 64 + fr, brow = wc * 64 + fr;

    auto stage = [&](const short* Ap, const short* Bp, int cur) {
        short* ad = As + cur * 4096;
        short* bd = Bs + cur * 4096;
        __builtin_amdgcn_global_load_lds(GAS(Ap + (long)sr * 512 + scc),
                                         LAS(ad + sr * 32 + (tid & 3) * 8), 16, 0, 0);
        __builtin_amdgcn_global_load_lds(GAS(Ap + (long)(sr + 64) * 512 + scc),
                                         LAS(ad + (sr + 64) * 32 + (tid & 3) * 8), 16, 0, 0);
        __builtin_amdgcn_global_load_lds(GAS(Bp + (long)sr * 512 + scc),
                                         LAS(bd + sr * 32 + (tid & 3) * 8), 16, 0, 0);
        __builtin_amdgcn_global_load_lds(GAS(Bp + (long)(sr + 64) * 512 + scc),
                                         LAS(bd + (sr + 64) * 32 + (tid & 3) * 8), 16, 0, 0);
    };

    f32x4 acc[4][4] = {};
    stage(A, B, 0);
    __syncthreads();
    for (int ks = 0; ks < 16; ++ks) {
        const int cur = ks & 1;
        if (ks + 1 < 16) stage(A + (ks + 1) * 32, B + (ks + 1) * 32, cur ^ 1);
        const short* pa = As + cur * 4096;
        const short* pb = Bs + cur * 4096;
        short8 af[4], bf[4];
#pragma unroll
        for (int mi = 0; mi < 4; ++mi) {
            const int row = arow + mi * 16;
            af[mi] = *(const short8*)&pa[row * 32 + ((fk ^ (row & 3)) * 8)];
        }
#pragma unroll
        for (int ni = 0; ni < 4; ++ni) {
            const int row = brow + ni * 16;
            bf[ni] = *(const short8*)&pb[row * 32 + ((fk ^ (row & 3)) * 8)];
        }
#pragma unroll
        for (int mi = 0; mi < 4; ++mi)
#pragma unroll
            for (int ni = 0; ni < 4; ++ni)
                acc[mi][ni] = MFMA(af[mi], bf[ni], acc[mi][ni], 0, 0, 0);
        __syncthreads();
    }

#pragma unroll
    for (int mi = 0; mi < 4; ++mi)
#pragma unroll
        for (int ni = 0; ni < 4; ++ni)
#pragma unroll
            for (int r = 0; r < 4; ++r)
                acc[mi][ni][r] = exp2f(acc[mi][ni][r] * kscale);

#pragma unroll
    for (int mi = 0; mi < 4; ++mi)
#pragma unroll
        for (int r = 0; r < 4; ++r) {
            float s = acc[mi][0][r] + acc[mi][1][r] + acc[mi][2][r] + acc[mi][3][r];
            s += __shfl_xor(s, 1); s += __shfl_xor(s, 2);
            s += __shfl_xor(s, 4); s += __shfl_xor(s, 8);
            if (fr == 0)
                lpart[((long)z * 32 + by * 2 + wc) * 2048 +
                      (long)bx * 128 + wr * 64 + mi * 16 + fk * 4 + r] = s;
        }

    short vals[4][4][4];
#pragma unroll
    for (int mi = 0; mi < 4; ++mi)
#pragma unroll
        for (int ni = 0; ni < 4; ++ni)
#pragma unroll
            for (int r = 0; r < 4; ++r)
                vals[mi][ni][r] = bf16_of(acc[mi][ni][r]);

    short* Cb = Sc + (long)z * 2048 * 2048 +
                (long)bx * 128 * 2048 + (long)by * 128;
    bounce_store(lds, vals, Cb, 2048);
}

// ---------- P @ V, in-kernel l reduction (BK=64 core, XCD-pinned) ----------
struct POff { long v[6], c[6]; };

__global__ __launch_bounds__(256, 2)
void pv_div(const short* __restrict__ Sc, const short* __restrict__ VT,
            const float* __restrict__ lpart, short* __restrict__ F,
            POff o, int z0, int zmask, int zshift) {
    __shared__ short sA[2 * 8192], sB[2 * 8192];
    const int bid = blockIdx.x;
    const int z = bid & zmask;
    const int t = bid >> zshift;
    const int bx = t & 15, by = t >> 4;
    const int slice = z0 + z;
    const int gp = slice >> 2, b = slice & 3;
    const short* Ab = Sc + (long)z * 2048 * 2048 + (long)bx * 128 * 2048;
    const short* Bb = VT + o.v[gp] + (long)b * 2048 + (long)by * 128 * 24576;
    f32x4 acc[4][4] = {};
    gemm_core64(Ab, 2048, Bb, 24576, 32, sA, sB, acc);

    const int tid = threadIdx.x, lane = tid & 63, wid = tid >> 6;
    const int wr = wid >> 1, wc = wid & 1, fr = lane & 15, fk = lane >> 4;

    float* linv_s = (float*)sB;
    if (tid < 128) {
        const float* lp = lpart + ((long)z * 32) * 2048 + (long)bx * 128 + tid;
        float s = 0.f;
#pragma unroll
        for (int j = 0; j < 32; ++j) s += lp[(long)j * 2048];
        linv_s[tid] = 1.0f / s;
    }
    __syncthreads();

    short vals[4][4][4];
#pragma unroll
    for (int mi = 0; mi < 4; ++mi) {
        float linv[4];
#pragma unroll
        for (int r = 0; r < 4; ++r) linv[r] = linv_s[wr * 64 + mi * 16 + fk * 4 + r];
#pragma unroll
        for (int ni = 0; ni < 4; ++ni)
#pragma unroll
            for (int r = 0; r < 4; ++r)
                vals[mi][ni][r] = bf16_of(acc[mi][ni][r] * linv[r]);
    }
    __syncthreads();

    short* Cb = F + ((long)b * 2048 + (long)bx * 128) * 3072 +
                o.c[gp] + (long)by * 128;
    bounce_store(sA, vals, Cb, 3072);
}

// ============================================================================
// final: d_out[8192][512] = fused[8192][3072] @ WoT2^T + bo (f32).
// 128x64 tiles -> grid (64,8) = 512 blocks, 3 blocks/CU.
// ============================================================================
__device__ __forceinline__ void stage_f(const short* A, const short* B,
                                        short* As, short* Bs) {
    const int tid = threadIdx.x, w = tid >> 6, l = tid & 63;
    const int r = l >> 3, scol = ((l & 7) ^ r) * 8;
#pragma unroll
    for (int q = 0; q < 4; ++q) {
        const int rowb = q * 32 + w * 8;
        __builtin_amdgcn_global_load_lds(GAS(A + (long)(rowb + r) * 3072 + scol),
                                         LAS(As + rowb * 64), 16, 0, 0);
    }
#pragma unroll
    for (int q = 0; q < 2; ++q) {
        const int rowb = q * 32 + w * 8;
        __builtin_amdgcn_global_load_lds(GAS(B + (long)(rowb + r) * 3072 + scol),
                                         LAS(Bs + rowb * 64), 16, 0, 0);
    }
}

__global__ __launch_bounds__(256, 3)
void final64(const short* __restrict__ A, const short* __restrict__ B,
             float* __restrict__ C, const float* __restrict__ bias) {
    __shared__ short sA[2 * 8192], sB[2 * 4096];
    const short* Ab = A + (long)blockIdx.x * 128 * 3072;
    const short* Bb = B + (long)blockIdx.y * 64 * 3072;
    const int tid = threadIdx.x, lane = tid & 63, w = tid >> 6;
    const int fr = lane & 15, fk = lane >> 4;
    const int swz = (fr & 7) << 4;
    const int abase = (w * 32 + fr) * 128 + fk * 16;
    const int bbase = fr * 128 + fk * 16;

    f32x4 acc[2][4] = {};
    stage_f(Ab, Bb, sA, sB);
    __syncthreads();
    for (int ks = 0; ks < 48; ++ks) {
        const int cur = ks & 1;
        if (ks + 1 < 48)
            stage_f(Ab + (ks + 1) * 64, Bb + (ks + 1) * 64,
                    sA + (cur ^ 1) * 8192, sB + (cur ^ 1) * 4096);
        const char* pa = (const char*)(sA + cur * 8192);
        const char* pb = (const char*)(sB + cur * 4096);
        short8 af[2][2], bf[2][4];
#pragma unroll
        for (int kk = 0; kk < 2; ++kk) {
#pragma unroll
            for (int mi = 0; mi < 2; ++mi)
                af[kk][mi] = *(const short8*)(pa + (((abase + kk * 64) ^ swz) + mi * 2048));
#pragma unroll
            for (int ni = 0; ni < 4; ++ni)
                bf[kk][ni] = *(const short8*)(pb + (((bbase + kk * 64) ^ swz) + ni * 2048));
        }
#pragma unroll
        for (int kk = 0; kk < 2; ++kk)
#pragma unroll
            for (int mi = 0; mi < 2; ++mi)
#pragma unroll
                for (int ni = 0; ni < 4; ++ni)
                    acc[mi][ni] = MFMA(af[kk][mi], bf[kk][ni], acc[mi][ni], 0, 0, 0);
        __syncthreads();
    }
    const long r0 = (long)blockIdx.x * 128 + w * 32 + fk * 4;
    const long c0 = (long)blockIdx.y * 64 + fr;
#pragma unroll
    for (int mi = 0; mi < 2; ++mi)
#pragma unroll
        for (int ni = 0; ni < 4; ++ni) {
            const long rr = r0 + mi * 16, cc = c0 + ni * 16;
#pragma unroll
            for (int r = 0; r < 4; ++r)
                C[(rr + r) * 512 + cc] = acc[mi][ni][r] + bias[cc];
        }
}

// ---------- f32 -> bf16 convert of x1,x2,x3 ----------
__global__ __launch_bounds__(256)
void xconv(const float* __restrict__ x0, const float* __restrict__ x1,
           const float* __restrict__ x2, short* __restrict__ xb) {
    const float* s = blockIdx.z == 0 ? x0 : (blockIdx.z == 1 ? x1 : x2);
    const long i = ((long)blockIdx.x * 256 + threadIdx.x) * 8;
    f32x4 a = *(const f32x4*)(s + i), c = *(const f32x4*)(s + i + 4);
    short8 v;
    v[0] = bf16_of(a.x); v[1] = bf16_of(a.y); v[2] = bf16_of(a.z); v[3] = bf16_of(a.w);
    v[4] = bf16_of(c.x); v[5] = bf16_of(c.y); v[6] = bf16_of(c.z); v[7] = bf16_of(c.w);
    *(short8*)(xb + (long)blockIdx.z * 8192 * 512 + i) = v;
}

// ---------- all weight transposes in one launch ----------
__global__ __launch_bounds__(256)
void wprep(const float* __restrict__ Wq, const float* __restrict__ Wk,
           const float* __restrict__ Wv, const float* __restrict__ Wo,
           short* __restrict__ WqkT, short* __restrict__ WvT,
           short* __restrict__ WoT2) {
    __shared__ float t[32][33];
    const int z = blockIdx.z;
    const float* src; short* dst; int rows; long ldd; bool dup = false;
    if (z == 0)      { src = Wq; dst = WqkT;              rows = 512;  ldd = 512; }
    else if (z == 1) { src = Wk; dst = WqkT + 512L * 512; rows = 512;  ldd = 512; }
    else if (z == 2) { src = Wv; dst = WvT;               rows = 512;  ldd = 512; }
    else             { src = Wo; dst = WoT2;              rows = 1536; ldd = 3072; dup = true; }
    const int r0 = blockIdx.x * 32, c0 = blockIdx.y * 32;
    if (r0 >= rows) return;
    const int lx = threadIdx.x & 31, ly = threadIdx.x >> 5;
#pragma unroll
    for (int p = 0; p < 4; ++p)
        t[ly + 8 * p][lx] = src[(long)(r0 + ly + 8 * p) * 512 + (c0 + lx)];
    __syncthreads();
#pragma unroll
    for (int p = 0; p < 4; ++p) {
        const short v = bf16_of(t[lx][ly + 8 * p]);
        const long base = (long)(c0 + ly + 8 * p) * ldd + (r0 + lx);
        dst[base] = v;
        if (dup) dst[base + 1536] = v;
    }
}

// ============================================================================
extern "C" void kernel_launch(void* const* d_in, const int* in_sizes, int n_in,
                              void* d_out, int out_size, void* d_ws, size_t ws_size,
                              hipStream_t stream) {
    const float* x[3] = { (const float*)d_in[0], (const float*)d_in[1], (const float*)d_in[2] };
    const float* Wq = (const float*)d_in[3]; const float* bq = (const float*)d_in[4];
    const float* Wk = (const float*)d_in[5]; const float* bk = (const float*)d_in[6];
    const float* Wv = (const float*)d_in[7]; const float* bv = (const float*)d_in[8];
    const float* Wo = (const float*)d_in[9]; const float* bo = (const float*)d_in[10];

    const long TOK = 8192, T3 = 3 * TOK;

    char* ws = (char*)d_ws;
    size_t off = 0;
    auto alloc = [&](size_t bytes) -> void* {
        void* pp = ws + off;
        off += (bytes + 255) & ~(size_t)255;
        return pp;
    };

    short* WqkT  = (short*)alloc(1024L * 512 * 2);        // [1024][512] = [WqT; WkT]
    short* WvT   = (short*)alloc(512L * 512 * 2);
    short* WoT2  = (short*)alloc(512L * 3072 * 2);        // [512][3072] = [WoT | WoT]
    short* Qb    = (short*)alloc(T3 * 512 * 2);           // [24576][512]
    short* Kb    = (short*)alloc(T3 * 512 * 2);           // [24576][512]
    short* VT    = (short*)alloc(512L * T3 * 2);          // [512][24576]
    short* fused = (short*)alloc(TOK * 3072 * 2);         // [8192][3072]
    float* lpart = (float*)alloc(8L * 32 * 2048 * 4);     // per-chunk partials
    short* xb    = (short*)alloc(T3 * 512 * 2);

    const size_t SLICE = 2048L * 2048 * 2;                // 8.39 MB
    const size_t rem = ws_size > off ? ws_size - off : 0;
    const int nsl = (rem >= 8 * SLICE) ? 8 : 4;
    const int zshift = (nsl == 8) ? 3 : 2;
    short* scores = (short*)alloc((size_t)nsl * SLICE);

    const dim3 tb(256);
    wprep<<<dim3(48, 16, 4), tb, 0, stream>>>(Wq, Wk, Wv, Wo, WqkT, WvT, WoT2);
    xconv<<<dim3(2048, 1, 3), tb, 0, stream>>>(x[0], x[1], x[2], xb);

    proj_qk_k<<<dim3(192, 8), tb, 0, stream>>>(xb, WqkT, Qb, Kb, bq, bk);
    proj_vt_k<<<dim3(4, 192), tb, 0, stream>>>(WvT, xb, VT, bv);

    // pairs: i attends to j. gp 0..2 -> fused cols [im*512); gp 3..5 -> +1536.
    const int imap[6] = {0, 1, 2, 0, 1, 2};
    const int jmap[6] = {1, 0, 0, 2, 2, 1};
    Off6 qo{}; POff po{};
    for (int gp = 0; gp < 6; ++gp) {
        qo.a[gp] = (long)imap[gp] * TOK * 512;
        qo.b[gp] = (long)jmap[gp] * TOK * 512;
        po.v[gp] = (long)jmap[gp] * TOK;
        po.c[gp] = (long)imap[gp] * 512 + (gp >= 3 ? 1536 : 0);
    }
    const float kscale = 0.04419417382415922f * 1.4426950408889634f; // 1/sqrt(512)*log2e

    for (int z0 = 0; z0 < 24; z0 += nsl) {
        qk_exp<<<dim3(256 * nsl), tb, 0, stream>>>(Qb, Kb, scores, lpart, qo,
                                                   z0, nsl - 1, zshift, kscale);
        pv_div<<<dim3(64 * nsl), tb, 0, stream>>>(scores, VT, lpart, fused, po,
                                                  z0, nsl - 1, zshift);
    }

    final64<<<dim3(64, 8), tb, 0, stream>>>(fused, WoT2, (float*)d_out, bo);
}